// Round 9
// baseline (273.377 us; speedup 1.0000x reference)
//
#include <hip/hip_runtime.h>
#include <hip/hip_bf16.h>

#define Hdim 256
#define Tdim 256
#define Bdim 512
#define TT   64
#define NTILE (Tdim / TT)   // 4
#define NTHR 256

typedef __attribute__((ext_vector_type(8))) short s16x8;
typedef __attribute__((ext_vector_type(4))) float f32x4;
typedef unsigned short u16;
typedef unsigned int u32;

__device__ __forceinline__ u16 f2bf_rne(float x) {
    u32 u = __builtin_bit_cast(u32, x);
    u32 r = u + 0x7FFFu + ((u >> 16) & 1u);
    return (u16)(r >> 16);
}
__device__ __forceinline__ float bf2f(u16 h) {
    u32 u = ((u32)h) << 16;
    return __builtin_bit_cast(float, u);
}
__device__ __forceinline__ u32 cvt_pk_bf16(float lo, float hi) {
    u32 r;
    asm("v_cvt_pk_bf16_f32 %0, %1, %2" : "=v"(r) : "v"(lo), "v"(hi));
    return r;
}
__device__ __forceinline__ f32x4 mfma16(s16x8 a, s16x8 b, f32x4 c) {
    return __builtin_amdgcn_mfma_f32_16x16x32_bf16(a, b, c, 0, 0, 0);
}
__device__ __forceinline__ float fast_tanh(float z) {
    float e = __expf(2.0f * z);
    return 1.0f - 2.0f / (e + 1.0f);
}

// ---------------- prep: split weights into bf16 hi/lo, packed B-fragment layout --
__global__ __launch_bounds__(256) void prep_weights(
        const float* __restrict__ W_Ih, const float* __restrict__ W_oI,
        u16* __restrict__ Wp1h, u16* __restrict__ Wp1l,
        u16* __restrict__ Wp2h, u16* __restrict__ Wp2l) {
    int idx = blockIdx.x * 256 + threadIdx.x;   // = o*256 + k
    if (idx >= Hdim * Hdim) return;
    int o = idx >> 8, k = idx & 255;
    int dst = (o >> 4) * 4096 + (k >> 5) * 512 + ((k >> 3) & 3) * 128 + (o & 15) * 8 + (k & 7);
    float w = W_Ih[idx];
    u16 hi = f2bf_rne(w);
    Wp1h[dst] = hi;
    Wp1l[dst] = f2bf_rne(w - bf2f(hi));
    w = W_oI[idx];
    hi = f2bf_rne(w);
    Wp2h[dst] = hi;
    Wp2l[dst] = f2bf_rne(w - bf2f(hi));
}

// ---------------- prep: cp[b,o] = h_hat @ W_I^T + b_I ----------------
__global__ __launch_bounds__(256) void cp_kernel(
        const float* __restrict__ h_tilde, const float* __restrict__ c_t,
        const float* __restrict__ W_I, const float* __restrict__ b_I,
        float* __restrict__ cp) {
    int b = blockIdx.x;
    int tid = threadIdx.x, w = tid >> 6, lane = tid & 63;
    __shared__ float hh[2 * Hdim];
    for (int i = tid; i < 2 * Hdim; i += 256)
        hh[i] = (i < Hdim) ? h_tilde[b * Hdim + i] : c_t[b * Hdim + i - Hdim];
    __syncthreads();
    for (int o = w; o < Hdim; o += 4) {
        float s = 0.f;
        const float* wr = W_I + (size_t)o * (2 * Hdim);
        #pragma unroll
        for (int k = lane; k < 2 * Hdim; k += 64) s += hh[k] * wr[k];
        #pragma unroll
        for (int d = 1; d < 64; d <<= 1) s += __shfl_xor(s, d, 64);
        if (lane == 0) cp[b * Hdim + o] = s + b_I[o];
    }
}

// ---------------- pass 1: scores for a 64-row tile per 256-thread block ----------
// 4 waves; wave w owns o-cols [w*64, w*64+64) (n=0..3), m=0..3 row-frags.
// LDS ~71KB -> 2 blocks/CU (8 waves/CU, 256-VGPR arch cap per wave).
// NEW (r9): explicit static-indexed weight prefetch pipelines (T14 reg-staged):
//   GEMM1 depth-2 (ks=0,1 issued before staging), GEMM2 depth-1 + prologue
//   issued during epilogue-1 -- hides the ~250cy L2 latency that capped r7/r8
//   at MfmaUtil ~22%.
__global__ __launch_bounds__(NTHR) void scores_kernel(
        const float* __restrict__ hist, const float* __restrict__ dT,
        const float* __restrict__ dL, const float* __restrict__ cp,
        const u16* __restrict__ Wp1h, const u16* __restrict__ Wp1l,
        const u16* __restrict__ Wp2h, const u16* __restrict__ Wp2l,
        const float* __restrict__ wI1T, const float* __restrict__ wI1L,
        const float* __restrict__ b_oI, const float* __restrict__ v_t,
        float* __restrict__ scores) {
    __shared__ u16 lds_u[2 * TT * Hdim];       // 64 KB: hist/Ihi + Ilo
    __shared__ float cpb[Hdim], wTb[Hdim], wLb[Hdim], bob[Hdim], vvb[Hdim]; // 5 KB
    __shared__ float dtl[TT], dll[TT];         // 0.5 KB
    __shared__ float sc_part[4][TT];           // 1 KB

    const int bid = blockIdx.x;
    const int b = bid >> 2;                    // NTILE = 4
    const int t0 = (bid & 3) * TT;
    const int tid = threadIdx.x;
    const int w = tid >> 6, lane = tid & 63;
    const int c = lane & 15, g = lane >> 4;
    const int ob = w * 64;                     // wave's 64-col o-slice

    const int wfrag = lane * 8;
    #define WOFF(n, ks) ((w * 4 + (n)) * 4096 + (ks) * 512 + wfrag)

    // ---- GEMM1 prefetch prologue: ks=0,1 issued BEFORE staging ------------------
    s16x8 b1h_a[4], b1l_a[4], b1h_b[4], b1l_b[4];
    #pragma unroll
    for (int n = 0; n < 4; ++n) {
        b1h_a[n] = *(const s16x8*)(Wp1h + WOFF(n, 0));
        b1l_a[n] = *(const s16x8*)(Wp1l + WOFF(n, 0));
        b1h_b[n] = *(const s16x8*)(Wp1h + WOFF(n, 1));
        b1l_b[n] = *(const s16x8*)(Wp1l + WOFF(n, 1));
    }

    // per-o constants into LDS
    for (int i = tid; i < Hdim; i += NTHR) {
        cpb[i] = cp[b * Hdim + i];
        wTb[i] = wI1T[i];
        wLb[i] = wI1L[i];
        bob[i] = b_oI[i];
        vvb[i] = v_t[i];
    }
    if (tid < TT) {
        dtl[tid] = dT[b * Tdim + t0 + tid];
        dll[tid] = dL[b * Tdim + t0 + tid];
    }

    // ---- stage hist tile: 64 rows x 256 cols fp32 -> bf16 swizzled --------------
    {
        const int srow = tid >> 2;
        const int sj = tid & 3;
        const float* srcb = hist + ((size_t)b * Tdim + t0 + srow) * Hdim;
        const u32 sbb = (u32)(srow * 512);
        const u32 ssz = (u32)((srow & 7) << 4);
        char* dst = (char*)lds_u;
        #pragma unroll
        for (int ch = 0; ch < 4; ++ch) {
            const int col = ch * 64 + sj * 16;
            float4 f0 = *(const float4*)(srcb + col + 0);
            float4 f1 = *(const float4*)(srcb + col + 4);
            float4 f2 = *(const float4*)(srcb + col + 8);
            float4 f3 = *(const float4*)(srcb + col + 12);
            uint4 ua = make_uint4(cvt_pk_bf16(f0.x, f0.y), cvt_pk_bf16(f0.z, f0.w),
                                  cvt_pk_bf16(f1.x, f1.y), cvt_pk_bf16(f1.z, f1.w));
            uint4 ub = make_uint4(cvt_pk_bf16(f2.x, f2.y), cvt_pk_bf16(f2.z, f2.w),
                                  cvt_pk_bf16(f3.x, f3.y), cvt_pk_bf16(f3.z, f3.w));
            *(uint4*)(dst + ((sbb + (u32)(col * 2) + 0) ^ ssz)) = ua;
            *(uint4*)(dst + ((sbb + (u32)(col * 2) + 16) ^ ssz)) = ub;
        }
    }
    __syncthreads();

    const f32x4 fz = {0.f, 0.f, 0.f, 0.f};
    const u32 swzA = (u32)((c & 7) << 4);

    // ================= GEMM1: depth-2 pipelined (2-pass split bf16) =============
    f32x4 acc[4][4];
    #pragma unroll
    for (int m = 0; m < 4; ++m)
        #pragma unroll
        for (int n = 0; n < 4; ++n) acc[m][n] = fz;
    {
        const char* hb = (const char*)lds_u;
        #pragma unroll
        for (int ks = 0; ks < 8; ++ks) {
            // consume current buffer (compile-time selection; loop fully unrolled)
            s16x8 cbh[4], cbl[4];
            #pragma unroll
            for (int n = 0; n < 4; ++n) {
                cbh[n] = (ks & 1) ? b1h_b[n] : b1h_a[n];
                cbl[n] = (ks & 1) ? b1l_b[n] : b1l_a[n];
            }
            // issue ks+2 loads before this step's MFMAs
            if (ks + 2 < 8) {
                #pragma unroll
                for (int n = 0; n < 4; ++n) {
                    if (ks & 1) {
                        b1h_b[n] = *(const s16x8*)(Wp1h + WOFF(n, ks + 2));
                        b1l_b[n] = *(const s16x8*)(Wp1l + WOFF(n, ks + 2));
                    } else {
                        b1h_a[n] = *(const s16x8*)(Wp1h + WOFF(n, ks + 2));
                        b1l_a[n] = *(const s16x8*)(Wp1l + WOFF(n, ks + 2));
                    }
                }
            }
            s16x8 a[4];
            #pragma unroll
            for (int m = 0; m < 4; ++m)
                a[m] = *(const s16x8*)(hb +
                    (((u32)((m * 16 + c) * 512 + g * 16 + ks * 64)) ^ swzA));
            #pragma unroll
            for (int n = 0; n < 4; ++n)
                #pragma unroll
                for (int m = 0; m < 4; ++m) {
                    acc[m][n] = mfma16(a[m], cbh[n], acc[m][n]);
                    acc[m][n] = mfma16(a[m], cbl[n], acc[m][n]);
                }
        }
    }
    __syncthreads();   // all hist reads done; region reusable for Ihi

    // ---- GEMM2 prefetch prologue: ks=0 in flight during epilogue-1 --------------
    s16x8 b2h_n[4], b2l_n[4];
    #pragma unroll
    for (int n = 0; n < 4; ++n) {
        b2h_n[n] = *(const s16x8*)(Wp2h + WOFF(n, 0));
        b2l_n[n] = *(const s16x8*)(Wp2l + WOFF(n, 0));
    }

    // ---- epilogue 1: z -> hi/lo bf16 (pair-pack via shfl), Ihi over hist --------
    {
        char* Ihi_b = (char*)lds_u;
        char* Ilo_b = (char*)lds_u + 32768;
        #pragma unroll
        for (int n = 0; n < 4; ++n) {
            const int o = ob + n * 16 + c;
            const float base_ = cpb[o], wt = wTb[o], wl = wLb[o];
            const u32 ocol2 = (u32)((o & ~1) * 2);
            #pragma unroll
            for (int m = 0; m < 4; ++m) {
                #pragma unroll
                for (int r = 0; r < 4; ++r) {
                    const int row = m * 16 + g * 4 + r;
                    float z = acc[m][n][r] + base_ + dtl[row] * wt + dll[row] * wl;
                    float zsw = __shfl_xor(z, 1, 64);
                    float z0 = (c & 1) ? zsw : z;
                    float z1 = (c & 1) ? z : zsw;
                    u32 hi2 = cvt_pk_bf16(z0, z1);
                    const u32 byteoff = ((u32)(row * 512) + ocol2) ^ ((u32)((row & 7) << 4));
                    if (!(c & 1)) {
                        *(u32*)(Ihi_b + byteoff) = hi2;
                    } else {
                        float h0 = __builtin_bit_cast(float, hi2 << 16);
                        float h1 = __builtin_bit_cast(float, hi2 & 0xFFFF0000u);
                        u32 lo2 = cvt_pk_bf16(z0 - h0, z1 - h1);
                        *(u32*)(Ilo_b + byteoff) = lo2;
                    }
                }
            }
        }
    }
    __syncthreads();   // Ihi/Ilo ready

    // ================= GEMM2: depth-1 pipelined (3-pass) ========================
    f32x4 acc2[4][4];
    #pragma unroll
    for (int m = 0; m < 4; ++m)
        #pragma unroll
        for (int n = 0; n < 4; ++n) acc2[m][n] = fz;
    {
        const char* Ihi_b = (const char*)lds_u;
        const char* Ilo_b = (const char*)lds_u + 32768;
        #pragma unroll
        for (int ks = 0; ks < 8; ++ks) {
            s16x8 cbh[4], cbl[4];
            #pragma unroll
            for (int n = 0; n < 4; ++n) { cbh[n] = b2h_n[n]; cbl[n] = b2l_n[n]; }
            if (ks + 1 < 8) {
                #pragma unroll
                for (int n = 0; n < 4; ++n) {
                    b2h_n[n] = *(const s16x8*)(Wp2h + WOFF(n, ks + 1));
                    b2l_n[n] = *(const s16x8*)(Wp2l + WOFF(n, ks + 1));
                }
            }
            s16x8 ah[4], al[4];
            #pragma unroll
            for (int m = 0; m < 4; ++m) {
                const u32 ad = ((u32)((m * 16 + c) * 512 + g * 16 + ks * 64)) ^ swzA;
                ah[m] = *(const s16x8*)(Ihi_b + ad);
                al[m] = *(const s16x8*)(Ilo_b + ad);
            }
            #pragma unroll
            for (int n = 0; n < 4; ++n)
                #pragma unroll
                for (int m = 0; m < 4; ++m) {
                    acc2[m][n] = mfma16(ah[m], cbh[n], acc2[m][n]);
                    acc2[m][n] = mfma16(ah[m], cbl[n], acc2[m][n]);
                    acc2[m][n] = mfma16(al[m], cbh[n], acc2[m][n]);
                }
        }
    }

    // ---- epilogue 2: tanh, dot v, reduce over c, then over waves -> scores ------
    {
        float bov[4], vvv[4];
        #pragma unroll
        for (int n = 0; n < 4; ++n) {
            const int o = ob + n * 16 + c;
            bov[n] = bob[o];
            vvv[n] = vvb[o];
        }
        #pragma unroll
        for (int m = 0; m < 4; ++m) {
            #pragma unroll
            for (int r = 0; r < 4; ++r) {
                float s = 0.f;
                #pragma unroll
                for (int n = 0; n < 4; ++n) {
                    float z = acc2[m][n][r] + bov[n];
                    s += fast_tanh(z) * vvv[n];
                }
                s += __shfl_xor(s, 1, 64);
                s += __shfl_xor(s, 2, 64);
                s += __shfl_xor(s, 4, 64);
                s += __shfl_xor(s, 8, 64);
                if (c == 0) sc_part[w][m * 16 + g * 4 + r] = s;
            }
        }
    }
    __syncthreads();
    if (tid < TT) {
        float s = sc_part[0][tid] + sc_part[1][tid] + sc_part[2][tid] + sc_part[3][tid];
        scores[b * Tdim + t0 + tid] = s;
    }
    #undef WOFF
}

// ---------------- pass 2: softmax + alpha + s_t = alpha^T . hist ----------------
__global__ __launch_bounds__(512) void finish_kernel(
        const float* __restrict__ hist, float* __restrict__ out) {
    const int b = blockIdx.x;
    const int tid = threadIdx.x;
    const int w = tid >> 6, lane = tid & 63;
    __shared__ float al_sh[Tdim];
    __shared__ float wred[4], wsum[4];
    __shared__ float part[Hdim];

    float* scores = out + Bdim * Hdim;
    float sc = 0.f;
    if (tid < Tdim) {
        sc = scores[b * Tdim + tid];
        float mx = sc;
        #pragma unroll
        for (int d = 1; d < 64; d <<= 1) mx = fmaxf(mx, __shfl_xor(mx, d, 64));
        if (lane == 0) wred[w] = mx;
    }
    __syncthreads();
    const float mx = fmaxf(fmaxf(wred[0], wred[1]), fmaxf(wred[2], wred[3]));
    float e = 0.f;
    if (tid < Tdim) {
        e = __expf(sc - mx);
        float ss = e;
        #pragma unroll
        for (int d = 1; d < 64; d <<= 1) ss += __shfl_xor(ss, d, 64);
        if (lane == 0) wsum[w] = ss;
    }
    __syncthreads();
    const float l = wsum[0] + wsum[1] + wsum[2] + wsum[3];
    if (tid < Tdim) {
        const float a = e / l;
        al_sh[tid] = a;
        scores[b * Tdim + tid] = a;   // alpha output (in-place over scores)
    }
    __syncthreads();

    const int h = tid & 255, half = tid >> 8;
    const float* hp = hist + (size_t)b * (Tdim * Hdim) + (size_t)half * 128 * Hdim + h;
    float s0 = 0.f, s1 = 0.f, s2 = 0.f, s3 = 0.f;
    #pragma unroll 4
    for (int t = 0; t < 128; t += 4) {
        const int tb = half * 128 + t;
        s0 += al_sh[tb + 0] * hp[(size_t)(t + 0) * Hdim];
        s1 += al_sh[tb + 1] * hp[(size_t)(t + 1) * Hdim];
        s2 += al_sh[tb + 2] * hp[(size_t)(t + 2) * Hdim];
        s3 += al_sh[tb + 3] * hp[(size_t)(t + 3) * Hdim];
    }
    const float s = (s0 + s1) + (s2 + s3);
    if (half == 0) part[h] = s;
    __syncthreads();
    if (half == 1) out[b * Hdim + h] = part[h] + s;
}

extern "C" void kernel_launch(void* const* d_in, const int* in_sizes, int n_in,
                              void* d_out, int out_size, void* d_ws, size_t ws_size,
                              hipStream_t stream) {
    const float* h_tilde = (const float*)d_in[0];
    const float* c_t     = (const float*)d_in[1];
    const float* hist    = (const float*)d_in[2];
    const float* dT      = (const float*)d_in[3];
    const float* dL      = (const float*)d_in[4];
    const float* W_I     = (const float*)d_in[5];
    const float* W_Ih    = (const float*)d_in[6];
    const float* W_I1T   = (const float*)d_in[7];
    const float* W_I1L   = (const float*)d_in[8];
    const float* b_I     = (const float*)d_in[9];
    const float* W_oI    = (const float*)d_in[10];
    const float* b_oI    = (const float*)d_in[11];
    const float* v_t     = (const float*)d_in[12];
    float* out = (float*)d_out;

    char* ws = (char*)d_ws;
    float* cp  = (float*)ws;                          // 512 KB
    u16* Wp1h = (u16*)(ws + 524288);                  // 128 KB each
    u16* Wp1l = (u16*)(ws + 524288 + 131072);
    u16* Wp2h = (u16*)(ws + 524288 + 2 * 131072);
    u16* Wp2l = (u16*)(ws + 524288 + 3 * 131072);
    float* scores = out + Bdim * Hdim;                // raw scores into alpha slot

    prep_weights<<<dim3(256), dim3(256), 0, stream>>>(W_Ih, W_oI, Wp1h, Wp1l, Wp2h, Wp2l);
    cp_kernel<<<dim3(Bdim), dim3(256), 0, stream>>>(h_tilde, c_t, W_I, b_I, cp);
    scores_kernel<<<dim3(Bdim * NTILE), dim3(NTHR), 0, stream>>>(
        hist, dT, dL, cp, Wp1h, Wp1l, Wp2h, Wp2l, W_I1T, W_I1L, b_oI, v_t, scores);
    finish_kernel<<<dim3(Bdim), dim3(512), 0, stream>>>(hist, out);
}

// Round 10
// 166.154 us; speedup vs baseline: 1.6453x; 1.6453x over previous
//
#include <hip/hip_runtime.h>
#include <hip/hip_bf16.h>

#define Hdim 256
#define Tdim 256
#define Bdim 512
#define TT   64
#define NTILE (Tdim / TT)   // 4
#define NTHR 256

typedef __attribute__((ext_vector_type(8))) short s16x8;
typedef __attribute__((ext_vector_type(4))) float f32x4;
typedef unsigned short u16;
typedef unsigned int u32;

__device__ __forceinline__ u16 f2bf_rne(float x) {
    u32 u = __builtin_bit_cast(u32, x);
    u32 r = u + 0x7FFFu + ((u >> 16) & 1u);
    return (u16)(r >> 16);
}
__device__ __forceinline__ float bf2f(u16 h) {
    u32 u = ((u32)h) << 16;
    return __builtin_bit_cast(float, u);
}
__device__ __forceinline__ u32 cvt_pk_bf16(float lo, float hi) {
    u32 r;
    asm("v_cvt_pk_bf16_f32 %0, %1, %2" : "=v"(r) : "v"(lo), "v"(hi));
    return r;
}
__device__ __forceinline__ f32x4 mfma16(s16x8 a, s16x8 b, f32x4 c) {
    return __builtin_amdgcn_mfma_f32_16x16x32_bf16(a, b, c, 0, 0, 0);
}
__device__ __forceinline__ float fast_tanh(float z) {
    float e = __expf(2.0f * z);
    return 1.0f - 2.0f / (e + 1.0f);
}

// ---- prep A: Wcomb = W_oI @ W_Ih in fp32, packed-split to bf16 hi/lo; wT2/wL2 ----
// Wcomb[o,k] = sum_i W_oI[o,i] * W_Ih[i,k]. Block o, thread j=k.
// Packed dst (same B-frag layout as all prior rounds):
//   dst = (o>>4)*4096 + (k>>5)*512 + ((k>>3)&3)*128 + (o&15)*8 + (k&7)
__global__ __launch_bounds__(256) void prep_wcomb(
        const float* __restrict__ W_Ih, const float* __restrict__ W_oI,
        const float* __restrict__ W_I1T, const float* __restrict__ W_I1L,
        u16* __restrict__ Wph, u16* __restrict__ Wpl,
        float* __restrict__ wT2, float* __restrict__ wL2) {
    const int o = blockIdx.x;
    const int j = threadIdx.x;
    const int w = j >> 6, lane = j & 63;
    __shared__ float sWo[Hdim];
    __shared__ float redT[4], redL[4];
    sWo[j] = W_oI[o * Hdim + j];
    __syncthreads();

    float acc = 0.f;
    #pragma unroll 8
    for (int i = 0; i < Hdim; ++i)
        acc += sWo[i] * W_Ih[i * Hdim + j];
    const int dst = (o >> 4) * 4096 + (j >> 5) * 512 + ((j >> 3) & 3) * 128
                  + (o & 15) * 8 + (j & 7);
    u16 hi = f2bf_rne(acc);
    Wph[dst] = hi;
    Wpl[dst] = f2bf_rne(acc - bf2f(hi));

    // wT2[o] = sum_i W_oI[o,i]*W_I1T[i];  wL2 likewise
    float pT = sWo[j] * W_I1T[j];
    float pL = sWo[j] * W_I1L[j];
    #pragma unroll
    for (int d = 1; d < 64; d <<= 1) {
        pT += __shfl_xor(pT, d, 64);
        pL += __shfl_xor(pL, d, 64);
    }
    if (lane == 0) { redT[w] = pT; redL[w] = pL; }
    __syncthreads();
    if (j == 0) {
        wT2[o] = redT[0] + redT[1] + redT[2] + redT[3];
        wL2[o] = redL[0] + redL[1] + redL[2] + redL[3];
    }
}

// ---- prep B: cp2[b,o] = (h_hat @ W_I^T + b_I) @ W_oI^T + b_oI ----
__global__ __launch_bounds__(256) void cp2_kernel(
        const float* __restrict__ h_tilde, const float* __restrict__ c_t,
        const float* __restrict__ W_I, const float* __restrict__ b_I,
        const float* __restrict__ W_oI, const float* __restrict__ b_oI,
        float* __restrict__ cp2) {
    int b = blockIdx.x;
    int tid = threadIdx.x, w = tid >> 6, lane = tid & 63;
    __shared__ float hh[2 * Hdim];
    __shared__ float cpl[Hdim];
    for (int i = tid; i < 2 * Hdim; i += 256)
        hh[i] = (i < Hdim) ? h_tilde[b * Hdim + i] : c_t[b * Hdim + i - Hdim];
    __syncthreads();
    for (int o = w; o < Hdim; o += 4) {
        float s = 0.f;
        const float* wr = W_I + (size_t)o * (2 * Hdim);
        #pragma unroll
        for (int k = lane; k < 2 * Hdim; k += 64) s += hh[k] * wr[k];
        #pragma unroll
        for (int d = 1; d < 64; d <<= 1) s += __shfl_xor(s, d, 64);
        if (lane == 0) cpl[o] = s + b_I[o];
    }
    __syncthreads();
    for (int o = w; o < Hdim; o += 4) {
        float s = 0.f;
        const float* wr = W_oI + (size_t)o * Hdim;
        #pragma unroll
        for (int k = lane; k < Hdim; k += 64) s += cpl[k] * wr[k];
        #pragma unroll
        for (int d = 1; d < 64; d <<= 1) s += __shfl_xor(s, d, 64);
        if (lane == 0) cp2[b * Hdim + o] = s + b_oI[o];
    }
}

// ---- pass 1: scores via SINGLE collapsed GEMM (2-pass split bf16) --------------
// z[t,o] = hist[t,:].Wcomb[o,:] + cp2[b,o] + dt[t]*wT2[o] + dl[t]*wL2[o]
// 256 thr = 4 waves; wave w owns o-cols [w*64,w*64+64) (n=0..3), m=0..3 row-frags.
// LDS ~34KB -> 4 blocks/CU (vs r8's 2): double the cross-block latency hiding.
// No GEMM2, no epilogue-1 (hi/lo split + shfl pair-pack deleted).
__global__ __launch_bounds__(NTHR) void scores_kernel(
        const float* __restrict__ hist, const float* __restrict__ dT,
        const float* __restrict__ dL, const float* __restrict__ cp2,
        const u16* __restrict__ Wph, const u16* __restrict__ Wpl,
        const float* __restrict__ wT2, const float* __restrict__ wL2,
        const float* __restrict__ v_t, float* __restrict__ scores) {
    __shared__ u16 lds_u[TT * Hdim];           // 32 KB hist tile
    __shared__ float dtl[TT], dll[TT];         // 0.5 KB
    __shared__ float sc_part[4][TT];           // 1 KB

    const int bid = blockIdx.x;
    const int b = bid >> 2;                    // NTILE = 4
    const int t0 = (bid & 3) * TT;
    const int tid = threadIdx.x;
    const int w = tid >> 6, lane = tid & 63;
    const int c = lane & 15, g = lane >> 4;
    const int ob = w * 64;

    // per-lane epilogue constants (16 regs): o = ob + n*16 + c
    float cpv[4], wtv[4], wlv[4], vvv[4];
    #pragma unroll
    for (int n = 0; n < 4; ++n) {
        const int o = ob + n * 16 + c;
        cpv[n] = cp2[b * Hdim + o];
        wtv[n] = wT2[o];
        wlv[n] = wL2[o];
        vvv[n] = v_t[o];
    }
    if (tid < TT) {
        dtl[tid] = dT[b * Tdim + t0 + tid];
        dll[tid] = dL[b * Tdim + t0 + tid];
    }

    // ---- stage hist tile: 64 rows x 256 cols fp32 -> bf16 swizzled --------------
    {
        const int srow = tid >> 2;
        const int sj = tid & 3;
        const float* srcb = hist + ((size_t)b * Tdim + t0 + srow) * Hdim;
        const u32 sbb = (u32)(srow * 512);
        const u32 ssz = (u32)((srow & 7) << 4);
        char* dst = (char*)lds_u;
        #pragma unroll
        for (int ch = 0; ch < 4; ++ch) {
            const int col = ch * 64 + sj * 16;
            float4 f0 = *(const float4*)(srcb + col + 0);
            float4 f1 = *(const float4*)(srcb + col + 4);
            float4 f2 = *(const float4*)(srcb + col + 8);
            float4 f3 = *(const float4*)(srcb + col + 12);
            uint4 ua = make_uint4(cvt_pk_bf16(f0.x, f0.y), cvt_pk_bf16(f0.z, f0.w),
                                  cvt_pk_bf16(f1.x, f1.y), cvt_pk_bf16(f1.z, f1.w));
            uint4 ub = make_uint4(cvt_pk_bf16(f2.x, f2.y), cvt_pk_bf16(f2.z, f2.w),
                                  cvt_pk_bf16(f3.x, f3.y), cvt_pk_bf16(f3.z, f3.w));
            *(uint4*)(dst + ((sbb + (u32)(col * 2) + 0) ^ ssz)) = ua;
            *(uint4*)(dst + ((sbb + (u32)(col * 2) + 16) ^ ssz)) = ub;
        }
    }
    __syncthreads();

    const f32x4 fz = {0.f, 0.f, 0.f, 0.f};
    const u32 swzA = (u32)((c & 7) << 4);

    // ================= GEMM: z = hist @ (Wch+Wcl)^T (2-pass split bf16) =========
    f32x4 acc[4][4];
    #pragma unroll
    for (int m = 0; m < 4; ++m)
        #pragma unroll
        for (int n = 0; n < 4; ++n) acc[m][n] = fz;
    {
        const char* hb = (const char*)lds_u;
        #pragma unroll
        for (int ks = 0; ks < 8; ++ks) {
            s16x8 a[4];
            #pragma unroll
            for (int m = 0; m < 4; ++m)
                a[m] = *(const s16x8*)(hb +
                    (((u32)((m * 16 + c) * 512 + g * 16 + ks * 64)) ^ swzA));
            #pragma unroll
            for (int n = 0; n < 4; ++n) {
                const int wo = (w * 4 + n) * 4096 + ks * 512 + lane * 8;
                const s16x8 bh = *(const s16x8*)(Wph + wo);
                const s16x8 bl = *(const s16x8*)(Wpl + wo);
                #pragma unroll
                for (int m = 0; m < 4; ++m) {
                    acc[m][n] = mfma16(a[m], bh, acc[m][n]);
                    acc[m][n] = mfma16(a[m], bl, acc[m][n]);
                }
            }
        }
    }

    // ---- epilogue: z -> tanh -> dot v -> reduce over c, then waves --------------
    #pragma unroll
    for (int m = 0; m < 4; ++m) {
        #pragma unroll
        for (int r = 0; r < 4; ++r) {
            const int row = m * 16 + g * 4 + r;
            const float dtr = dtl[row], dlr = dll[row];
            float s = 0.f;
            #pragma unroll
            for (int n = 0; n < 4; ++n) {
                float z = acc[m][n][r] + cpv[n] + dtr * wtv[n] + dlr * wlv[n];
                s += fast_tanh(z) * vvv[n];
            }
            s += __shfl_xor(s, 1, 64);
            s += __shfl_xor(s, 2, 64);
            s += __shfl_xor(s, 4, 64);
            s += __shfl_xor(s, 8, 64);
            if (c == 0) sc_part[w][row] = s;
        }
    }
    __syncthreads();
    if (tid < TT) {
        float s = sc_part[0][tid] + sc_part[1][tid] + sc_part[2][tid] + sc_part[3][tid];
        scores[b * Tdim + t0 + tid] = s;
    }
}

// ---------------- pass 2: softmax + alpha + s_t = alpha^T . hist ----------------
__global__ __launch_bounds__(512) void finish_kernel(
        const float* __restrict__ hist, float* __restrict__ out) {
    const int b = blockIdx.x;
    const int tid = threadIdx.x;
    const int w = tid >> 6, lane = tid & 63;
    __shared__ float al_sh[Tdim];
    __shared__ float wred[4], wsum[4];
    __shared__ float part[Hdim];

    float* scores = out + Bdim * Hdim;
    float sc = 0.f;
    if (tid < Tdim) {
        sc = scores[b * Tdim + tid];
        float mx = sc;
        #pragma unroll
        for (int d = 1; d < 64; d <<= 1) mx = fmaxf(mx, __shfl_xor(mx, d, 64));
        if (lane == 0) wred[w] = mx;
    }
    __syncthreads();
    const float mx = fmaxf(fmaxf(wred[0], wred[1]), fmaxf(wred[2], wred[3]));
    float e = 0.f;
    if (tid < Tdim) {
        e = __expf(sc - mx);
        float ss = e;
        #pragma unroll
        for (int d = 1; d < 64; d <<= 1) ss += __shfl_xor(ss, d, 64);
        if (lane == 0) wsum[w] = ss;
    }
    __syncthreads();
    const float l = wsum[0] + wsum[1] + wsum[2] + wsum[3];
    if (tid < Tdim) {
        const float a = e / l;
        al_sh[tid] = a;
        scores[b * Tdim + tid] = a;   // alpha output (in-place over scores)
    }
    __syncthreads();

    const int h = tid & 255, half = tid >> 8;
    const float* hp = hist + (size_t)b * (Tdim * Hdim) + (size_t)half * 128 * Hdim + h;
    float s0 = 0.f, s1 = 0.f, s2 = 0.f, s3 = 0.f;
    #pragma unroll 4
    for (int t = 0; t < 128; t += 4) {
        const int tb = half * 128 + t;
        s0 += al_sh[tb + 0] * hp[(size_t)(t + 0) * Hdim];
        s1 += al_sh[tb + 1] * hp[(size_t)(t + 1) * Hdim];
        s2 += al_sh[tb + 2] * hp[(size_t)(t + 2) * Hdim];
        s3 += al_sh[tb + 3] * hp[(size_t)(t + 3) * Hdim];
    }
    const float s = (s0 + s1) + (s2 + s3);
    if (half == 0) part[h] = s;
    __syncthreads();
    if (half == 1) out[b * Hdim + h] = part[h] + s;
}

extern "C" void kernel_launch(void* const* d_in, const int* in_sizes, int n_in,
                              void* d_out, int out_size, void* d_ws, size_t ws_size,
                              hipStream_t stream) {
    const float* h_tilde = (const float*)d_in[0];
    const float* c_t     = (const float*)d_in[1];
    const float* hist    = (const float*)d_in[2];
    const float* dT      = (const float*)d_in[3];
    const float* dL      = (const float*)d_in[4];
    const float* W_I     = (const float*)d_in[5];
    const float* W_Ih    = (const float*)d_in[6];
    const float* W_I1T   = (const float*)d_in[7];
    const float* W_I1L   = (const float*)d_in[8];
    const float* b_I     = (const float*)d_in[9];
    const float* W_oI    = (const float*)d_in[10];
    const float* b_oI    = (const float*)d_in[11];
    const float* v_t     = (const float*)d_in[12];
    float* out = (float*)d_out;

    char* ws = (char*)d_ws;
    u16* Wph   = (u16*)ws;                            // 128 KB
    u16* Wpl   = (u16*)(ws + 131072);                 // 128 KB
    float* cp2 = (float*)(ws + 262144);               // 512 KB
    float* wT2 = (float*)(ws + 786432);               // 1 KB
    float* wL2 = (float*)(ws + 787456);               // 1 KB
    float* scores = out + Bdim * Hdim;                // raw scores into alpha slot

    prep_wcomb<<<dim3(Hdim), dim3(256), 0, stream>>>(W_Ih, W_oI, W_I1T, W_I1L,
                                                     Wph, Wpl, wT2, wL2);
    cp2_kernel<<<dim3(Bdim), dim3(256), 0, stream>>>(h_tilde, c_t, W_I, b_I,
                                                     W_oI, b_oI, cp2);
    scores_kernel<<<dim3(Bdim * NTILE), dim3(NTHR), 0, stream>>>(
        hist, dT, dL, cp2, Wph, Wpl, wT2, wL2, v_t, scores);
    finish_kernel<<<dim3(Bdim), dim3(512), 0, stream>>>(hist, out);
}

// Round 11
// 145.830 us; speedup vs baseline: 1.8746x; 1.1394x over previous
//
#include <hip/hip_runtime.h>
#include <hip/hip_bf16.h>

#define Hdim 256
#define Tdim 256
#define Bdim 512
#define TT   64
#define NTILE (Tdim / TT)   // 4
#define NTHR 256

typedef __attribute__((ext_vector_type(8))) short s16x8;
typedef __attribute__((ext_vector_type(4))) float f32x4;
typedef unsigned short u16;
typedef unsigned int u32;

__device__ __forceinline__ u16 f2bf_rne(float x) {
    u32 u = __builtin_bit_cast(u32, x);
    u32 r = u + 0x7FFFu + ((u >> 16) & 1u);
    return (u16)(r >> 16);
}
__device__ __forceinline__ float bf2f(u16 h) {
    u32 u = ((u32)h) << 16;
    return __builtin_bit_cast(float, u);
}
__device__ __forceinline__ u32 cvt_pk_bf16(float lo, float hi) {
    u32 r;
    asm("v_cvt_pk_bf16_f32 %0, %1, %2" : "=v"(r) : "v"(lo), "v"(hi));
    return r;
}
__device__ __forceinline__ f32x4 mfma16(s16x8 a, s16x8 b, f32x4 c) {
    return __builtin_amdgcn_mfma_f32_16x16x32_bf16(a, b, c, 0, 0, 0);
}
__device__ __forceinline__ float fast_tanh(float z) {
    float e = __expf(2.0f * z);
    return 1.0f - 2.0f / (e + 1.0f);
}

// ---- prep A: Wcomb = W_oI @ W_Ih in fp32, packed-split to bf16 hi/lo; wT2/wL2 ----
// 4 independent accumulators break the r10 serial-FMA-chain (256 x 4cy dep).
__global__ __launch_bounds__(256) void prep_wcomb(
        const float* __restrict__ W_Ih, const float* __restrict__ W_oI,
        const float* __restrict__ W_I1T, const float* __restrict__ W_I1L,
        u16* __restrict__ Wph, u16* __restrict__ Wpl,
        float* __restrict__ wT2, float* __restrict__ wL2) {
    const int o = blockIdx.x;
    const int j = threadIdx.x;
    const int w = j >> 6, lane = j & 63;
    __shared__ float sWo[Hdim];
    __shared__ float redT[4], redL[4];
    sWo[j] = W_oI[o * Hdim + j];
    __syncthreads();

    float a0 = 0.f, a1 = 0.f, a2 = 0.f, a3 = 0.f;
    #pragma unroll 8
    for (int i = 0; i < Hdim; i += 4) {
        a0 += sWo[i + 0] * W_Ih[(i + 0) * Hdim + j];
        a1 += sWo[i + 1] * W_Ih[(i + 1) * Hdim + j];
        a2 += sWo[i + 2] * W_Ih[(i + 2) * Hdim + j];
        a3 += sWo[i + 3] * W_Ih[(i + 3) * Hdim + j];
    }
    const float acc = (a0 + a1) + (a2 + a3);
    const int dst = (o >> 4) * 4096 + (j >> 5) * 512 + ((j >> 3) & 3) * 128
                  + (o & 15) * 8 + (j & 7);
    u16 hi = f2bf_rne(acc);
    Wph[dst] = hi;
    Wpl[dst] = f2bf_rne(acc - bf2f(hi));

    float pT = sWo[j] * W_I1T[j];
    float pL = sWo[j] * W_I1L[j];
    #pragma unroll
    for (int d = 1; d < 64; d <<= 1) {
        pT += __shfl_xor(pT, d, 64);
        pL += __shfl_xor(pL, d, 64);
    }
    if (lane == 0) { redT[w] = pT; redL[w] = pL; }
    __syncthreads();
    if (j == 0) {
        wT2[o] = redT[0] + redT[1] + redT[2] + redT[3];
        wL2[o] = redL[0] + redL[1] + redL[2] + redL[3];
    }
}

// ---- prep B: cp2[b,o] = (h_hat @ W_I^T + b_I) @ W_oI^T + b_oI ----
__global__ __launch_bounds__(256) void cp2_kernel(
        const float* __restrict__ h_tilde, const float* __restrict__ c_t,
        const float* __restrict__ W_I, const float* __restrict__ b_I,
        const float* __restrict__ W_oI, const float* __restrict__ b_oI,
        float* __restrict__ cp2) {
    int b = blockIdx.x;
    int tid = threadIdx.x, w = tid >> 6, lane = tid & 63;
    __shared__ float hh[2 * Hdim];
    __shared__ float cpl[Hdim];
    for (int i = tid; i < 2 * Hdim; i += 256)
        hh[i] = (i < Hdim) ? h_tilde[b * Hdim + i] : c_t[b * Hdim + i - Hdim];
    __syncthreads();
    for (int o = w; o < Hdim; o += 4) {
        float s = 0.f;
        const float* wr = W_I + (size_t)o * (2 * Hdim);
        #pragma unroll
        for (int k = lane; k < 2 * Hdim; k += 64) s += hh[k] * wr[k];
        #pragma unroll
        for (int d = 1; d < 64; d <<= 1) s += __shfl_xor(s, d, 64);
        if (lane == 0) cpl[o] = s + b_I[o];
    }
    __syncthreads();
    for (int o = w; o < Hdim; o += 4) {
        float s = 0.f;
        const float* wr = W_oI + (size_t)o * Hdim;
        #pragma unroll
        for (int k = lane; k < Hdim; k += 64) s += cpl[k] * wr[k];
        #pragma unroll
        for (int d = 1; d < 64; d <<= 1) s += __shfl_xor(s, d, 64);
        if (lane == 0) cp2[b * Hdim + o] = s + b_oI[o];
    }
}

// ---- pass 1: collapsed GEMM -> scores + per-tile softmax partials (flash-style) --
// z[t,o] = hist.Wcomb^T + cp2 + dt*wT2 + dl*wL2; sc = sum_o tanh(z)*v.
// Then tile-local: m_k, l_k, S_k[256] = sum_t e^{sc-m_k} hist[t,:] (from the LDS
// bf16 tile already staged) -> ws. Kills finish_kernel's 128MB hist re-read.
__global__ __launch_bounds__(NTHR) void scores_kernel(
        const float* __restrict__ hist, const float* __restrict__ dT,
        const float* __restrict__ dL, const float* __restrict__ cp2,
        const u16* __restrict__ Wph, const u16* __restrict__ Wpl,
        const float* __restrict__ wT2, const float* __restrict__ wL2,
        const float* __restrict__ v_t, float* __restrict__ scores,
        float* __restrict__ Spart, float* __restrict__ mpart,
        float* __restrict__ lpart) {
    __shared__ u16 lds_u[TT * Hdim];           // 32 KB hist tile (bf16, swizzled)
    __shared__ float dtl[TT], dll[TT];         // 0.5 KB
    __shared__ float sc_part[4][TT];           // 1 KB
    __shared__ float p_sh[TT];                 // 0.25 KB
    __shared__ float ml_sh[2];
    __shared__ float sacc2[2][Hdim];           // 2 KB

    const int bid = blockIdx.x;
    const int b = bid >> 2;                    // NTILE = 4
    const int t0 = (bid & 3) * TT;
    const int tid = threadIdx.x;
    const int w = tid >> 6, lane = tid & 63;
    const int c = lane & 15, g = lane >> 4;
    const int ob = w * 64;

    float cpv[4], wtv[4], wlv[4], vvv[4];
    #pragma unroll
    for (int n = 0; n < 4; ++n) {
        const int o = ob + n * 16 + c;
        cpv[n] = cp2[b * Hdim + o];
        wtv[n] = wT2[o];
        wlv[n] = wL2[o];
        vvv[n] = v_t[o];
    }
    if (tid < TT) {
        dtl[tid] = dT[b * Tdim + t0 + tid];
        dll[tid] = dL[b * Tdim + t0 + tid];
    }

    // ---- stage hist tile: 64 rows x 256 cols fp32 -> bf16 swizzled --------------
    {
        const int srow = tid >> 2;
        const int sj = tid & 3;
        const float* srcb = hist + ((size_t)b * Tdim + t0 + srow) * Hdim;
        const u32 sbb = (u32)(srow * 512);
        const u32 ssz = (u32)((srow & 7) << 4);
        char* dst = (char*)lds_u;
        #pragma unroll
        for (int ch = 0; ch < 4; ++ch) {
            const int col = ch * 64 + sj * 16;
            float4 f0 = *(const float4*)(srcb + col + 0);
            float4 f1 = *(const float4*)(srcb + col + 4);
            float4 f2 = *(const float4*)(srcb + col + 8);
            float4 f3 = *(const float4*)(srcb + col + 12);
            uint4 ua = make_uint4(cvt_pk_bf16(f0.x, f0.y), cvt_pk_bf16(f0.z, f0.w),
                                  cvt_pk_bf16(f1.x, f1.y), cvt_pk_bf16(f1.z, f1.w));
            uint4 ub = make_uint4(cvt_pk_bf16(f2.x, f2.y), cvt_pk_bf16(f2.z, f2.w),
                                  cvt_pk_bf16(f3.x, f3.y), cvt_pk_bf16(f3.z, f3.w));
            *(uint4*)(dst + ((sbb + (u32)(col * 2) + 0) ^ ssz)) = ua;
            *(uint4*)(dst + ((sbb + (u32)(col * 2) + 16) ^ ssz)) = ub;
        }
    }
    __syncthreads();

    const f32x4 fz = {0.f, 0.f, 0.f, 0.f};
    const u32 swzA = (u32)((c & 7) << 4);

    // ================= GEMM: z = hist @ (Wch+Wcl)^T (2-pass split bf16) =========
    f32x4 acc[4][4];
    #pragma unroll
    for (int m = 0; m < 4; ++m)
        #pragma unroll
        for (int n = 0; n < 4; ++n) acc[m][n] = fz;
    {
        const char* hb = (const char*)lds_u;
        #pragma unroll
        for (int ks = 0; ks < 8; ++ks) {
            s16x8 a[4];
            #pragma unroll
            for (int m = 0; m < 4; ++m)
                a[m] = *(const s16x8*)(hb +
                    (((u32)((m * 16 + c) * 512 + g * 16 + ks * 64)) ^ swzA));
            #pragma unroll
            for (int n = 0; n < 4; ++n) {
                const int wo = (w * 4 + n) * 4096 + ks * 512 + lane * 8;
                const s16x8 bh = *(const s16x8*)(Wph + wo);
                const s16x8 bl = *(const s16x8*)(Wpl + wo);
                #pragma unroll
                for (int m = 0; m < 4; ++m) {
                    acc[m][n] = mfma16(a[m], bh, acc[m][n]);
                    acc[m][n] = mfma16(a[m], bl, acc[m][n]);
                }
            }
        }
    }

    // ---- epilogue: tanh -> dot v -> per-row partial scores ----------------------
    #pragma unroll
    for (int m = 0; m < 4; ++m) {
        #pragma unroll
        for (int r = 0; r < 4; ++r) {
            const int row = m * 16 + g * 4 + r;
            const float dtr = dtl[row], dlr = dll[row];
            float s = 0.f;
            #pragma unroll
            for (int n = 0; n < 4; ++n) {
                float z = acc[m][n][r] + cpv[n] + dtr * wtv[n] + dlr * wlv[n];
                s += fast_tanh(z) * vvv[n];
            }
            s += __shfl_xor(s, 1, 64);
            s += __shfl_xor(s, 2, 64);
            s += __shfl_xor(s, 4, 64);
            s += __shfl_xor(s, 8, 64);
            if (c == 0) sc_part[w][row] = s;
        }
    }
    __syncthreads();

    // ---- tile softmax partials (wave 0) -----------------------------------------
    if (tid < TT) {
        float s = sc_part[0][tid] + sc_part[1][tid] + sc_part[2][tid] + sc_part[3][tid];
        scores[b * Tdim + t0 + tid] = s;      // raw score (combine reads it)
        float mx = s;
        #pragma unroll
        for (int d = 1; d < 64; d <<= 1) mx = fmaxf(mx, __shfl_xor(mx, d, 64));
        float p = __expf(s - mx);
        float l = p;
        #pragma unroll
        for (int d = 1; d < 64; d <<= 1) l += __shfl_xor(l, d, 64);
        p_sh[tid] = p;
        if (tid == 0) { ml_sh[0] = mx; ml_sh[1] = l; }
    }
    __syncthreads();

    // ---- S_k[o] = sum_t p_t * hist[t,o]  (from staged bf16 LDS tile) ------------
    {
        const int half = tid >> 7;             // t in [half*32, half*32+32)
        const int pp = tid & 127;              // col pair (2*pp, 2*pp+1)
        const char* hb = (const char*)lds_u;
        float s0 = 0.f, s1 = 0.f;
        #pragma unroll 8
        for (int i = 0; i < 32; ++i) {
            const int t = half * 32 + i;
            const float pv = p_sh[t];          // wave-uniform broadcast
            const u32 hw = *(const u32*)(hb + (((u32)(t * 512 + pp * 4)) ^ ((u32)((t & 7) << 4))));
            s0 += pv * __builtin_bit_cast(float, hw << 16);
            s1 += pv * __builtin_bit_cast(float, hw & 0xFFFF0000u);
        }
        sacc2[half][2 * pp] = s0;
        sacc2[half][2 * pp + 1] = s1;
    }
    __syncthreads();
    Spart[(size_t)bid * Hdim + tid] = sacc2[0][tid] + sacc2[1][tid];
    if (tid == 0) { mpart[bid] = ml_sh[0]; lpart[bid] = ml_sh[1]; }
}

// ---- pass 2: combine 4 tile-partials per batch -> s_t and alpha -----------------
__global__ __launch_bounds__(256) void combine_kernel(
        const float* __restrict__ Spart, const float* __restrict__ mpart,
        const float* __restrict__ lpart, float* __restrict__ out) {
    const int b = blockIdx.x;
    const int tid = threadIdx.x;
    __shared__ float fsh[4], inv_l_sh, m_sh;
    if (tid == 0) {
        const float m0 = mpart[4 * b + 0], m1 = mpart[4 * b + 1];
        const float m2 = mpart[4 * b + 2], m3 = mpart[4 * b + 3];
        const float m = fmaxf(fmaxf(m0, m1), fmaxf(m2, m3));
        const float f0 = __expf(m0 - m), f1 = __expf(m1 - m);
        const float f2 = __expf(m2 - m), f3 = __expf(m3 - m);
        const float l = f0 * lpart[4 * b + 0] + f1 * lpart[4 * b + 1]
                      + f2 * lpart[4 * b + 2] + f3 * lpart[4 * b + 3];
        fsh[0] = f0; fsh[1] = f1; fsh[2] = f2; fsh[3] = f3;
        inv_l_sh = 1.0f / l;
        m_sh = m;
    }
    __syncthreads();
    const float inv_l = inv_l_sh;
    const float S = fsh[0] * Spart[(size_t)(4 * b + 0) * Hdim + tid]
                  + fsh[1] * Spart[(size_t)(4 * b + 1) * Hdim + tid]
                  + fsh[2] * Spart[(size_t)(4 * b + 2) * Hdim + tid]
                  + fsh[3] * Spart[(size_t)(4 * b + 3) * Hdim + tid];
    out[b * Hdim + tid] = S * inv_l;
    float* scores = out + Bdim * Hdim;         // raw scores -> alpha in place
    const float sc = scores[b * Tdim + tid];
    scores[b * Tdim + tid] = __expf(sc - m_sh) * inv_l;
}

extern "C" void kernel_launch(void* const* d_in, const int* in_sizes, int n_in,
                              void* d_out, int out_size, void* d_ws, size_t ws_size,
                              hipStream_t stream) {
    const float* h_tilde = (const float*)d_in[0];
    const float* c_t     = (const float*)d_in[1];
    const float* hist    = (const float*)d_in[2];
    const float* dT      = (const float*)d_in[3];
    const float* dL      = (const float*)d_in[4];
    const float* W_I     = (const float*)d_in[5];
    const float* W_Ih    = (const float*)d_in[6];
    const float* W_I1T   = (const float*)d_in[7];
    const float* W_I1L   = (const float*)d_in[8];
    const float* b_I     = (const float*)d_in[9];
    const float* W_oI    = (const float*)d_in[10];
    const float* b_oI    = (const float*)d_in[11];
    const float* v_t     = (const float*)d_in[12];
    float* out = (float*)d_out;

    char* ws = (char*)d_ws;
    u16* Wph     = (u16*)ws;                          // 128 KB
    u16* Wpl     = (u16*)(ws + 131072);               // 128 KB
    float* cp2   = (float*)(ws + 262144);             // 512 KB
    float* wT2   = (float*)(ws + 786432);             // 1 KB
    float* wL2   = (float*)(ws + 787456);             // 1 KB
    float* Spart = (float*)(ws + 788480);             // 2 MB (2048 tiles x 256)
    float* mpart = (float*)(ws + 788480 + 2097152);   // 8 KB
    float* lpart = (float*)(ws + 788480 + 2105344);   // 8 KB
    float* scores = out + Bdim * Hdim;                // raw scores into alpha slot

    prep_wcomb<<<dim3(Hdim), dim3(256), 0, stream>>>(W_Ih, W_oI, W_I1T, W_I1L,
                                                     Wph, Wpl, wT2, wL2);
    cp2_kernel<<<dim3(Bdim), dim3(256), 0, stream>>>(h_tilde, c_t, W_I, b_I,
                                                     W_oI, b_oI, cp2);
    scores_kernel<<<dim3(Bdim * NTILE), dim3(NTHR), 0, stream>>>(
        hist, dT, dL, cp2, Wph, Wpl, wT2, wL2, v_t, scores, Spart, mpart, lpart);
    combine_kernel<<<dim3(Bdim), dim3(256), 0, stream>>>(Spart, mpart, lpart, out);
}